// Round 1
// baseline (226.566 us; speedup 1.0000x reference)
//
#include <hip/hip_runtime.h>

// Problem constants (from reference setup_inputs). Note W == H == 768 -> all
// x/y scales and centers coincide, so packed (x,y) math shares constants.
constexpr int N = 16, H = 768, W = 768;
constexpr int HW = H * W;
constexpr float EPS2 = 1.0e-6f;            // EPS^2, EPS = 0.001
constexpr float INV = 1.0f / 767.0f;       // 1/(W-1) == 1/(H-1)
constexpr float WM1 = 767.0f, WM2 = 766.0f, HM1 = 767.0f;
constexpr float CHALF  = 383.5f;           // (W-1)/2 : |c-383.5|<=383.5 <=> c in [0,767]
constexpr float CHALFI = 383.0f;           // (W-2)/2 : |c-383|  <=383   <=> c in [0,766]

// Round-8 geometry: 64 cols x 32 rows output per 512-thread block (8 waves),
// halo 8 cols / 4 rows. Interleaved {fx,fy} per pixel.
// LSTRIDE padded 80->84: row stride = 168 words == 8 (mod 32 banks) so rows
// y and y+1 never alias LDS banks (row-alias on gathers was the dominant
// SQ_LDS_BANK_CONFLICT source at LSTRIDE=80 where stride == 0 mod 32).
// LDS = 2*40*84*2*4 = 53760 B = exactly 105 x 512B granules -> 3 blocks/CU
// x 8 waves = 24 waves/CU (75% occupancy cap, was 62.5%).
constexpr int TILE_COLS = 80;              // staged (real) cols: [bx0-8, bx0+72)
constexpr int TILE_ROWS = 40;              // staged rows: [by0-4, by0+36)
constexpr int C_HALO = 8;
constexpr int R_HALO = 4;
constexpr int LSTRIDE = 84;                // padded leading dim (words = pixels)
constexpr int TILE_FLOATS = TILE_ROWS * LSTRIDE * 2;  // 6720 floats per tensor
constexpr int NBLK_X = W / 64, NBLK_Y = H / 32;       // 12, 24
constexpr int NBLOCKS = NBLK_X * NBLK_Y * N;          // 4608

// packed-fp32 pair: arithmetic on this type emits v_pk_{add,mul,fma}_f32
typedef float v2f __attribute__((ext_vector_type(2)));
// 8-byte vector with 4-byte alignment promise (planar global fallback)
typedef float float2a __attribute__((ext_vector_type(2), aligned(4)));

struct DirMeta { v2f g; v2f f0; int xb, y0, y1; };

__device__ __forceinline__ void dir_meta(v2f flow, v2f xy, DirMeta& m) {
    m.g = xy + flow;                                   // 1 pk_add
    m.f0 = (v2f){floorf(m.g.x), floorf(m.g.y)};
    m.xb = (int)fminf(fmaxf(m.f0.x, 0.0f), WM2);       // med3 + cvt
    m.y0 = (int)fminf(fmaxf(m.f0.y, 0.0f), HM1);
    m.y1 = (int)fminf(fmaxf(m.f0.y + 1.0f, 0.0f), HM1); // NOT min(y0+1,..): y0f=-1 case
}

// ---------- fast path ------------------------------------------------------
// Quads: u0={fx,fy}@(y0,xb), v0=@(y0,xb+1), u1=@(y1,xb), v1=@(y1,xb+1).
// Eligible iff outer floor in [0,W-2]x[0,H-2] AND all 4 inner sample coords
// in [0,W-1]x[0,H-1] (then every validity mask is 1 and bilinear of the
// linear grid is the identity). Centered-abs form: compares use free |x|
// input modifiers; max-trees fuse to v_max3; diagonal corners pack.
__device__ __forceinline__ bool fast_ok(v2f f0, v2f u0, v2f v0, v2f u1, v2f v1) {
    v2f c  = f0 - CHALF;          // pk
    v2f c1 = c + 1.0f;            // pk
    v2f d00 = c  + u0;            // pk: corner (+0,+0)
    v2f d11 = c1 + v1;            // pk: corner (+1,+1)
    float d01x = c1.x + v0.x, d01y = c.y  + v0.y;   // corner (+1,+0)
    float d10x = c.x  + u1.x, d10y = c1.y + u1.y;   // corner (+0,+1)
    float xm = fmaxf(fabsf(d00.x), fabsf(d01x));
    xm = fmaxf(xm, fmaxf(fabsf(d10x), fabsf(d11.x)));   // v_max3
    float ym = fmaxf(fabsf(d00.y), fabsf(d01y));
    ym = fmaxf(ym, fmaxf(fabsf(d10y), fabsf(d11.y)));
    v2f t = c + 0.5f;             // pk: f0 - 383
    return (xm <= CHALF) & (ym <= CHALF)
         & (fabsf(t.x) <= CHALFI) & (fabsf(t.y) <= CHALFI);
}

// All-valid residual (bilerp of flow1, identity inner warp):
__device__ __forceinline__ float fast_eval(const DirMeta& m,
                                           v2f u0, v2f v0, v2f u1, v2f v1,
                                           v2f cen) {
    v2f w = m.g - m.f0;                       // (wx1, wy1), pk
    v2f wx = (v2f){w.x, w.x};
    v2f wy = (v2f){w.y, w.y};
    v2f ft = u0 + wx * (v0 - u0);             // pk_sub + pk_fma
    v2f fb = u1 + wx * (v1 - u1);
    v2f fv = ft + wy * (fb - ft);
    v2f r = (cen + fv) * INV;                 // pk_add + pk_mul
    return sqrtf(fmaf(r.x, r.x, fmaf(r.y, r.y, EPS2)));
}

// ---------- general (border / wild-flow) path (verified rounds 4-7) --------
__device__ __forceinline__ float2 wg(float fx, float fy, float xi, float yi) {
    float gx = xi + fx, gy = yi + fy;
    float x0 = floorf(gx), y0 = floorf(gy);
    float wx1 = gx - x0, wx0 = 1.0f - wx1;
    float wy1 = gy - y0, wy0 = 1.0f - wy1;
    float vx0 = (x0 >= 0.0f  && x0 <= WM1)        ? 1.0f : 0.0f;
    float vx1 = (x0 >= -1.0f && x0 <= WM1 - 1.0f) ? 1.0f : 0.0f;
    float vy0 = (y0 >= 0.0f  && y0 <= HM1)        ? 1.0f : 0.0f;
    float vy1 = (y0 >= -1.0f && y0 <= HM1 - 1.0f) ? 1.0f : 0.0f;
    float ax = wx0 * vx0, bx = wx1 * vx1, sx = ax + bx;
    float ay = wy0 * vy0, by = wy1 * vy1, sy = ay + by;
    float ms = sx * sy;
    float kx = (ms >= 0.9999f) ? INV : 0.0f;
    float ky = (ms >= 0.9999f) ? INV : 0.0f;
    float2 r;
    r.x = fmaf(sx, x0, bx) * sy * kx;
    r.y = fmaf(sy, y0, by) * sx * ky;
    return r;
}

__device__ __forceinline__ float dir_eval(const DirMeta& m,
                                          v2f u0, v2f v0, v2f u1, v2f v1,
                                          float xf, float yf) {
    float x0f = m.f0.x, y0f = m.f0.y;
    float wx1 = m.g.x - x0f, wx0 = 1.0f - wx1;
    float wy1 = m.g.y - y0f, wy0 = 1.0f - wy1;
    float x1f = x0f + 1.0f, y1f = y0f + 1.0f;
    float vx0 = (x0f >= 0.0f && x0f <= WM1) ? 1.0f : 0.0f;
    float vx1 = (x1f >= 0.0f && x1f <= WM1) ? 1.0f : 0.0f;
    float vy0 = (y0f >= 0.0f && y0f <= HM1) ? 1.0f : 0.0f;
    float vy1 = (y1f >= 0.0f && y1f <= HM1) ? 1.0f : 0.0f;
    float axw = wx0 * vx0, bxw = wx1 * vx1;
    float ayw = wy0 * vy0, byw = wy1 * vy1;
    float sxw = axw + bxw, syw = ayw + byw;
    float msum = sxw * syw;

    // gathered pair is at base xb = clamp(x0,0,W-2): select col within pair
    bool selA = (x0f >= WM1);
    bool selB = (x0f >= 0.0f);
    float fx00 = selA ? v0.x : u0.x;
    float fx01 = selB ? v0.x : u0.x;
    float fy00 = selA ? v0.y : u0.y;
    float fy01 = selB ? v0.y : u0.y;
    float fx10 = selA ? v1.x : u1.x;
    float fx11 = selB ? v1.x : u1.x;
    float fy10 = selA ? v1.y : u1.y;
    float fy11 = selB ? v1.y : u1.y;

    float x0c = fminf(fmaxf(x0f, 0.0f), WM1);
    float x1c = fminf(fmaxf(x1f, 0.0f), WM1);
    float y0c = fminf(fmaxf(y0f, 0.0f), HM1);
    float y1c = fminf(fmaxf(y1f, 0.0f), HM1);

    float2 m00 = wg(fx00, fy00, x0c, y0c);
    float2 m01 = wg(fx01, fy01, x1c, y0c);
    float2 m10 = wg(fx10, fy10, x0c, y1c);
    float2 m11 = wg(fx11, fy11, x1c, y1c);

    float w00 = axw * ayw, w10 = bxw * ayw, w01 = axw * byw, w11 = bxw * byw;
    float mx = w00 * m00.x + w10 * m01.x + w01 * m10.x + w11 * m11.x;
    float my = w00 * m00.y + w10 * m01.y + w01 * m10.y + w11 * m11.y;
    float keep = (msum >= 0.9999f) ? 1.0f : 0.0f;
    mx *= keep; my *= keep;

    float dx = xf * INV - mx;
    float dy = yf * INV - my;
    return sqrtf(fmaf(dx, dx, fmaf(dy, dy, EPS2)));
}

// Pixel pair (pix, pix+1) from interleaved tile: two adjacent 8B reads at one
// base -> fuses to ds_read2_b64.
__device__ __forceinline__ void ld_quad(const float* t, int pix, v2f& u, v2f& v) {
    u = *(const v2f*)(t + 2 * pix);
    v = *(const v2f*)(t + 2 * pix + 2);
}

__global__ __launch_bounds__(512)
void cycle_loss_kernel(const float* __restrict__ A,   // UV_AtoB
                       const float* __restrict__ B,   // UV_BtoA
                       float* __restrict__ ws,
                       float* __restrict__ out,
                       int use_ws) {
    __shared__ float lds[2 * TILE_FLOATS];   // [0]=A tile, [TILE_FLOATS]=B tile
                                             // (reused for wave sums at end)

    int tid  = threadIdx.x;
    int lane = tid & 63;
    int wv   = tid >> 6;                     // 0..7
    int bx0 = blockIdx.x * 64;
    int by0 = blockIdx.y * 32;
    int b   = blockIdx.z;
    const float* Ab = A + (size_t)b * 2 * HW;
    const float* Bb = B + (size_t)b * 2 * HW;
    int tc0 = bx0 - C_HALO;    // 16B-aligned
    int tr0 = by0 - R_HALO;

    // ---- stage both tensors as interleaved {fx,fy} tiles -----------------
    // 16B-unit tasks: one float4 LDS write per task; consecutive lanes write
    // consecutive 16B -> bank-minimal ds_write_b128 (8 words/bank floor).
    // Global side: 2 contiguous 8B loads per lane, fully coalesced per wave.
    constexpr int UNITS_PER_ROW = TILE_COLS / 2;          // 40
    constexpr int TASKS_PER_T = TILE_ROWS * UNITS_PER_ROW; // 1600
    for (int i = tid; i < 2 * TASKS_PER_T; i += 512) {
        int t   = i / TASKS_PER_T;
        int rem = i - t * TASKS_PER_T;
        int lr  = rem / UNITS_PER_ROW;
        int uc  = rem - lr * UNITS_PER_ROW;
        int rg = tr0 + lr;
        int cg = tc0 + uc * 2;
        if ((unsigned)rg < (unsigned)H && (unsigned)cg < (unsigned)W) {
            const float* src = (t ? Bb : Ab) + rg * W + cg;
            float2 fx = *(const float2*)(src);        // 8B-aligned (cg even)
            float2 fy = *(const float2*)(src + HW);
            *(float4*)&lds[t * TILE_FLOATS + (lr * LSTRIDE + uc * 2) * 2] =
                make_float4(fx.x, fy.x, fx.y, fy.y);
        }
    }
    __syncthreads();

    const float* ldsA = lds;
    const float* ldsB = lds + TILE_FLOATS;
    int x  = bx0 + lane;
    int yb = by0 + wv * 4;        // 4 consecutive rows per thread
    int lxc = lane + C_HALO;
    float xf = (float)x;

    // centers: one ds_read_b64 per tensor per pixel (2-way aliasing = free)
    v2f aC[4], bC[4];
    #pragma unroll
    for (int p = 0; p < 4; ++p) {
        int co = (wv * 4 + p + R_HALO) * LSTRIDE + lxc;
        aC[p] = *(const v2f*)(ldsA + 2 * co);
        bC[p] = *(const v2f*)(ldsB + 2 * co);
    }

    float s = 0.0f;
    #pragma unroll
    for (int p = 0; p < 4; ++p) {
        float yf = (float)(yb + p);
        v2f xy = (v2f){xf, yf};
        DirMeta m1, m2;
        dir_meta(bC[p], xy, m1);   // ABA: outer flow B, gather A
        dir_meta(aC[p], xy, m2);   // BAB: outer flow A, gather B

        // tile-local coords + eligibility (unsigned trick)
        int x1l = m1.xb - tc0, y1l0 = m1.y0 - tr0, y1l1 = m1.y1 - tr0;
        int x2l = m2.xb - tc0, y2l0 = m2.y0 - tr0, y2l1 = m2.y1 - tr0;
        bool e1 = ((unsigned)x1l <= (unsigned)(TILE_COLS - 2))
                & ((unsigned)y1l0 < (unsigned)TILE_ROWS)
                & ((unsigned)y1l1 < (unsigned)TILE_ROWS);
        bool e2 = ((unsigned)x2l <= (unsigned)(TILE_COLS - 2))
                & ((unsigned)y2l0 < (unsigned)TILE_ROWS)
                & ((unsigned)y2l1 < (unsigned)TILE_ROWS);

        v2f u10, v10, u11, v11, u20, v20, u21, v21;
        if (__all(e1 & e2)) {
            ld_quad(ldsA, y1l0 * LSTRIDE + x1l, u10, v10);
            ld_quad(ldsA, y1l1 * LSTRIDE + x1l, u11, v11);
            ld_quad(ldsB, y2l0 * LSTRIDE + x2l, u20, v20);
            ld_quad(ldsB, y2l1 * LSTRIDE + x2l, u21, v21);
        } else {
            // rare: per-lane LDS/global select
            if (e1) {
                ld_quad(ldsA, y1l0 * LSTRIDE + x1l, u10, v10);
                ld_quad(ldsA, y1l1 * LSTRIDE + x1l, u11, v11);
            } else {
                int o0 = m1.y0 * W + m1.xb, o1 = m1.y1 * W + m1.xb;
                float2a rx0 = *(const float2a*)(Ab + o0);
                float2a ry0 = *(const float2a*)(Ab + HW + o0);
                float2a rx1 = *(const float2a*)(Ab + o1);
                float2a ry1 = *(const float2a*)(Ab + HW + o1);
                u10 = (v2f){rx0.x, ry0.x}; v10 = (v2f){rx0.y, ry0.y};
                u11 = (v2f){rx1.x, ry1.x}; v11 = (v2f){rx1.y, ry1.y};
            }
            if (e2) {
                ld_quad(ldsB, y2l0 * LSTRIDE + x2l, u20, v20);
                ld_quad(ldsB, y2l1 * LSTRIDE + x2l, u21, v21);
            } else {
                int o0 = m2.y0 * W + m2.xb, o1 = m2.y1 * W + m2.xb;
                float2a rx0 = *(const float2a*)(Bb + o0);
                float2a ry0 = *(const float2a*)(Bb + HW + o0);
                float2a rx1 = *(const float2a*)(Bb + o1);
                float2a ry1 = *(const float2a*)(Bb + HW + o1);
                u20 = (v2f){rx0.x, ry0.x}; v20 = (v2f){rx0.y, ry0.y};
                u21 = (v2f){rx1.x, ry1.x}; v21 = (v2f){rx1.y, ry1.y};
            }
        }

        bool ok = fast_ok(m1.f0, u10, v10, u11, v11)
                & fast_ok(m2.f0, u20, v20, u21, v21);
        if (__all(ok)) {
            s += fast_eval(m1, u10, v10, u11, v11, bC[p]);
            s += fast_eval(m2, u20, v20, u21, v21, aC[p]);
        } else {
            s += dir_eval(m1, u10, v10, u11, v11, xf, yf);
            s += dir_eval(m2, u20, v20, u21, v21, xf, yf);
        }
    }

    // wave(64) shuffle reduce -> LDS (tile reuse) -> one value per block
    #pragma unroll
    for (int o = 32; o > 0; o >>= 1) s += __shfl_down(s, o, 64);
    __syncthreads();                 // all tile reads complete
    if (lane == 0) lds[wv] = s;
    __syncthreads();
    if (tid == 0) {
        float tsum = ((lds[0] + lds[1]) + (lds[2] + lds[3]))
                   + ((lds[4] + lds[5]) + (lds[6] + lds[7]));
        if (use_ws) {
            int bid = (blockIdx.z * gridDim.y + blockIdx.y) * gridDim.x + blockIdx.x;
            ws[bid] = tsum;                      // plain store, no atomics
        } else {
            atomicAdd(out, tsum * (1.0f / ((float)N * (float)H * (float)W)));
        }
    }
}

__global__ __launch_bounds__(256)
void reduce_kernel(const float* __restrict__ ws, float* __restrict__ out) {
    float s = 0.0f;
    for (int i = threadIdx.x; i < NBLOCKS / 4; i += 256) {   // float4 chunks
        float4 v = *(const float4*)(ws + 4 * i);
        s += (v.x + v.y) + (v.z + v.w);
    }
    #pragma unroll
    for (int o = 32; o > 0; o >>= 1) s += __shfl_down(s, o, 64);
    __shared__ float wsum[4];
    int lane = threadIdx.x & 63, wv = threadIdx.x >> 6;
    if (lane == 0) wsum[wv] = s;
    __syncthreads();
    if (threadIdx.x == 0) {
        float t = wsum[0] + wsum[1] + wsum[2] + wsum[3];
        out[0] = t * (1.0f / ((float)N * (float)H * (float)W));
    }
}

extern "C" void kernel_launch(void* const* d_in, const int* in_sizes, int n_in,
                              void* d_out, int out_size, void* d_ws, size_t ws_size,
                              hipStream_t stream) {
    const float* A = (const float*)d_in[0];   // UV_AtoB [16,2,768,768]
    const float* B = (const float*)d_in[1];   // UV_BtoA [16,2,768,768]
    float* out = (float*)d_out;               // scalar fp32
    float* ws  = (float*)d_ws;

    int use_ws = (ws_size >= NBLOCKS * sizeof(float)) ? 1 : 0;
    if (!use_ws) hipMemsetAsync(out, 0, sizeof(float), stream);

    dim3 grid(NBLK_X, NBLK_Y, N);             // (12, 24, 16) = 4608 blocks
    cycle_loss_kernel<<<grid, 512, 0, stream>>>(A, B, ws, out, use_ws);
    if (use_ws) reduce_kernel<<<1, 256, 0, stream>>>(ws, out);
}

// Round 2
// 220.717 us; speedup vs baseline: 1.0265x; 1.0265x over previous
//
#include <hip/hip_runtime.h>

// Problem constants (from reference setup_inputs). Note W == H == 768 -> all
// x/y scales and centers coincide, so packed (x,y) math shares constants.
constexpr int N = 16, H = 768, W = 768;
constexpr int HW = H * W;
constexpr float EPS2 = 1.0e-6f;            // EPS^2, EPS = 0.001
constexpr float INV = 1.0f / 767.0f;       // 1/(W-1) == 1/(H-1)
constexpr float WM1 = 767.0f, WM2 = 766.0f, HM1 = 767.0f;
constexpr float CHALF  = 383.5f;           // (W-1)/2 : |c-383.5|<=383.5 <=> c in [0,767]
constexpr float CHALFI = 383.0f;           // (W-2)/2 : |c-383|  <=383   <=> c in [0,766]

// Round-0 geometry (proven 92.5us) + LSTRIDE pad 80->84.
// 64 cols x 16 rows output per 256-thread block, halo 8 cols / 4 rows.
// LDS raw = 2*24*84*2*4 + 16 = 32272 -> granule 512B -> 32768B; x5 = 163840
// = exactly 160KiB -> 5 blocks/CU x 4 waves = 20 waves/CU (same cap as
// round-0). Row stride 168 words == 8 mod 32 banks: rows y/y+1 no longer
// bank-alias on gathers.
constexpr int TILE_COLS = 80;              // staged (real) cols: [bx0-8, bx0+72)
constexpr int TILE_ROWS = 24;              // staged rows: [by0-4, by0+20)
constexpr int C_HALO = 8;
constexpr int R_HALO = 4;
constexpr int LSTRIDE = 84;                // padded leading dim (pixels)
constexpr int TILE_FLOATS = TILE_ROWS * LSTRIDE * 2;  // 4032 floats per tensor
constexpr int MAXPIX = TILE_ROWS * LSTRIDE - 2;       // clamp for ld_quad
constexpr int NBLK_X = W / 64, NBLK_Y = H / 16;       // 12, 48
constexpr int NBLOCKS = NBLK_X * NBLK_Y * N;          // 9216

// packed-fp32 pair: arithmetic on this type emits v_pk_{add,mul,fma}_f32
typedef float v2f __attribute__((ext_vector_type(2)));
// 8-byte vector with 4-byte alignment promise (planar global fallback)
typedef float float2a __attribute__((ext_vector_type(2), aligned(4)));

struct DirMeta { v2f g; v2f f0; };         // slim: xb/y0/y1 recomputed on rare path

__device__ __forceinline__ void dir_meta(v2f flow, v2f xy, DirMeta& m) {
    m.g = xy + flow;                                   // 1 pk_add
    m.f0 = (v2f){floorf(m.g.x), floorf(m.g.y)};
}

// ---------- fast path ------------------------------------------------------
// Quads: u0={fx,fy}@(y0,xb), v0=@(y0,xb+1), u1=@(y1,xb), v1=@(y1,xb+1).
// Eligible iff outer floor in [0,W-2]x[0,H-2] AND all 4 inner sample coords
// in [0,W-1]x[0,H-1] (then every validity mask is 1 and bilinear of the
// linear grid is the identity). Centered-abs form: compares use free |x|
// input modifiers; max-trees fuse to v_max3; diagonal corners pack.
__device__ __forceinline__ bool fast_ok(v2f f0, v2f u0, v2f v0, v2f u1, v2f v1) {
    v2f c  = f0 - CHALF;          // pk
    v2f c1 = c + 1.0f;            // pk
    v2f d00 = c  + u0;            // pk: corner (+0,+0)
    v2f d11 = c1 + v1;            // pk: corner (+1,+1)
    float d01x = c1.x + v0.x, d01y = c.y  + v0.y;   // corner (+1,+0)
    float d10x = c.x  + u1.x, d10y = c1.y + u1.y;   // corner (+0,+1)
    float xm = fmaxf(fabsf(d00.x), fabsf(d01x));
    xm = fmaxf(xm, fmaxf(fabsf(d10x), fabsf(d11.x)));   // v_max3
    float ym = fmaxf(fabsf(d00.y), fabsf(d01y));
    ym = fmaxf(ym, fmaxf(fabsf(d10y), fabsf(d11.y)));
    v2f t = c + 0.5f;             // pk: f0 - 383
    return (xm <= CHALF) & (ym <= CHALF)
         & (fabsf(t.x) <= CHALFI) & (fabsf(t.y) <= CHALFI);
}

// All-valid residual (bilerp of flow1, identity inner warp):
__device__ __forceinline__ float fast_eval(const DirMeta& m,
                                           v2f u0, v2f v0, v2f u1, v2f v1,
                                           v2f cen) {
    v2f w = m.g - m.f0;                       // (wx1, wy1), pk
    v2f wx = (v2f){w.x, w.x};
    v2f wy = (v2f){w.y, w.y};
    v2f ft = u0 + wx * (v0 - u0);             // pk_sub + pk_fma
    v2f fb = u1 + wx * (v1 - u1);
    v2f fv = ft + wy * (fb - ft);
    v2f r = (cen + fv) * INV;                 // pk_add + pk_mul
    return sqrtf(fmaf(r.x, r.x, fmaf(r.y, r.y, EPS2)));
}

// ---------- general (border / wild-flow) path (verified rounds 4-7) --------
__device__ __forceinline__ float2 wg(float fx, float fy, float xi, float yi) {
    float gx = xi + fx, gy = yi + fy;
    float x0 = floorf(gx), y0 = floorf(gy);
    float wx1 = gx - x0, wx0 = 1.0f - wx1;
    float wy1 = gy - y0, wy0 = 1.0f - wy1;
    float vx0 = (x0 >= 0.0f  && x0 <= WM1)        ? 1.0f : 0.0f;
    float vx1 = (x0 >= -1.0f && x0 <= WM1 - 1.0f) ? 1.0f : 0.0f;
    float vy0 = (y0 >= 0.0f  && y0 <= HM1)        ? 1.0f : 0.0f;
    float vy1 = (y0 >= -1.0f && y0 <= HM1 - 1.0f) ? 1.0f : 0.0f;
    float ax = wx0 * vx0, bx = wx1 * vx1, sx = ax + bx;
    float ay = wy0 * vy0, by = wy1 * vy1, sy = ay + by;
    float ms = sx * sy;
    float kx = (ms >= 0.9999f) ? INV : 0.0f;
    float ky = (ms >= 0.9999f) ? INV : 0.0f;
    float2 r;
    r.x = fmaf(sx, x0, bx) * sy * kx;
    r.y = fmaf(sy, y0, by) * sx * ky;
    return r;
}

__device__ __forceinline__ float dir_eval(const DirMeta& m,
                                          v2f u0, v2f v0, v2f u1, v2f v1,
                                          float xf, float yf) {
    float x0f = m.f0.x, y0f = m.f0.y;
    float wx1 = m.g.x - x0f, wx0 = 1.0f - wx1;
    float wy1 = m.g.y - y0f, wy0 = 1.0f - wy1;
    float x1f = x0f + 1.0f, y1f = y0f + 1.0f;
    float vx0 = (x0f >= 0.0f && x0f <= WM1) ? 1.0f : 0.0f;
    float vx1 = (x1f >= 0.0f && x1f <= WM1) ? 1.0f : 0.0f;
    float vy0 = (y0f >= 0.0f && y0f <= HM1) ? 1.0f : 0.0f;
    float vy1 = (y1f >= 0.0f && y1f <= HM1) ? 1.0f : 0.0f;
    float axw = wx0 * vx0, bxw = wx1 * vx1;
    float ayw = wy0 * vy0, byw = wy1 * vy1;
    float sxw = axw + bxw, syw = ayw + byw;
    float msum = sxw * syw;

    // gathered pair is at base xb = clamp(x0,0,W-2): select col within pair
    bool selA = (x0f >= WM1);
    bool selB = (x0f >= 0.0f);
    float fx00 = selA ? v0.x : u0.x;
    float fx01 = selB ? v0.x : u0.x;
    float fy00 = selA ? v0.y : u0.y;
    float fy01 = selB ? v0.y : u0.y;
    float fx10 = selA ? v1.x : u1.x;
    float fx11 = selB ? v1.x : u1.x;
    float fy10 = selA ? v1.y : u1.y;
    float fy11 = selB ? v1.y : u1.y;

    float x0c = fminf(fmaxf(x0f, 0.0f), WM1);
    float x1c = fminf(fmaxf(x1f, 0.0f), WM1);
    float y0c = fminf(fmaxf(y0f, 0.0f), HM1);
    float y1c = fminf(fmaxf(y1f, 0.0f), HM1);

    float2 m00 = wg(fx00, fy00, x0c, y0c);
    float2 m01 = wg(fx01, fy01, x1c, y0c);
    float2 m10 = wg(fx10, fy10, x0c, y1c);
    float2 m11 = wg(fx11, fy11, x1c, y1c);

    float w00 = axw * ayw, w10 = bxw * ayw, w01 = axw * byw, w11 = bxw * byw;
    float mx = w00 * m00.x + w10 * m01.x + w01 * m10.x + w11 * m11.x;
    float my = w00 * m00.y + w10 * m01.y + w01 * m10.y + w11 * m11.y;
    float keep = (msum >= 0.9999f) ? 1.0f : 0.0f;
    mx *= keep; my *= keep;

    float dx = xf * INV - mx;
    float dy = yf * INV - my;
    return sqrtf(fmaf(dx, dx, fmaf(dy, dy, EPS2)));
}

// Pixel pair (pix, pix+1) from interleaved tile: two adjacent 8B reads at one
// base -> fuses to ds_read2_b64.
__device__ __forceinline__ void ld_quad(const float* t, int pix, v2f& u, v2f& v) {
    u = *(const v2f*)(t + 2 * pix);
    v = *(const v2f*)(t + 2 * pix + 2);
}

// Issue phase: UNCONDITIONAL clamped LDS gather (index clamp via v_min_u32;
// negative/OOB wraps to huge unsigned -> clamped). Garbage for ineligible
// lanes is overwritten by gather_fallback before any consumer.
__device__ __forceinline__ void gather_issue(const float* tile, const DirMeta& m,
                                             int tc0, int tr0, bool& e,
                                             v2f& u0, v2f& v0, v2f& u1, v2f& v1) {
    int xb = (int)fminf(fmaxf(m.f0.x, 0.0f), WM2);       // med3 + cvt
    int y0 = (int)fminf(fmaxf(m.f0.y, 0.0f), HM1);
    int y1 = (int)fminf(fmaxf(m.f0.y + 1.0f, 0.0f), HM1); // NOT y0+1: y0f=-1 case
    int xl = xb - tc0, yl0 = y0 - tr0, yl1 = y1 - tr0;
    e = ((unsigned)xl <= (unsigned)(TILE_COLS - 2))
      & ((unsigned)yl0 < (unsigned)TILE_ROWS)
      & ((unsigned)yl1 < (unsigned)TILE_ROWS);
    unsigned p0 = min((unsigned)(yl0 * LSTRIDE + xl), (unsigned)MAXPIX);
    unsigned p1 = min((unsigned)(yl1 * LSTRIDE + xl), (unsigned)MAXPIX);
    ld_quad(tile, (int)p0, u0, v0);
    ld_quad(tile, (int)p1, u1, v1);
}

// Rare path: per-lane global reload (border / wild flow), planar layout.
__device__ __forceinline__ void gather_fallback(const float* base, const DirMeta& m,
                                                v2f& u0, v2f& v0, v2f& u1, v2f& v1) {
    int xb = (int)fminf(fmaxf(m.f0.x, 0.0f), WM2);
    int y0 = (int)fminf(fmaxf(m.f0.y, 0.0f), HM1);
    int y1 = (int)fminf(fmaxf(m.f0.y + 1.0f, 0.0f), HM1);
    int o0 = y0 * W + xb, o1 = y1 * W + xb;
    float2a rx0 = *(const float2a*)(base + o0);
    float2a ry0 = *(const float2a*)(base + HW + o0);
    float2a rx1 = *(const float2a*)(base + o1);
    float2a ry1 = *(const float2a*)(base + HW + o1);
    u0 = (v2f){rx0.x, ry0.x}; v0 = (v2f){rx0.y, ry0.y};
    u1 = (v2f){rx1.x, ry1.x}; v1 = (v2f){rx1.y, ry1.y};
}

struct Pix {
    DirMeta m1, m2;
    bool e1, e2;
    v2f u10, v10, u11, v11, u20, v20, u21, v21;
};

__global__ __launch_bounds__(256, 4)
void cycle_loss_kernel(const float* __restrict__ A,   // UV_AtoB
                       const float* __restrict__ B,   // UV_BtoA
                       float* __restrict__ ws,
                       float* __restrict__ out,
                       int use_ws) {
    __shared__ float lds[2 * TILE_FLOATS];   // [0]=A tile, [TILE_FLOATS]=B tile
    __shared__ float wsum[4];

    int tid  = threadIdx.x;
    int lane = tid & 63;
    int wv   = tid >> 6;
    int bx0 = blockIdx.x * 64;
    int by0 = blockIdx.y * 16;
    int b   = blockIdx.z;
    const float* Ab = A + (size_t)b * 2 * HW;
    const float* Bb = B + (size_t)b * 2 * HW;
    int tc0 = bx0 - C_HALO;    // 16B-aligned
    int tr0 = by0 - R_HALO;

    // ---- stage both tensors as interleaved {fx,fy} tiles (round-0) -------
    constexpr int ROW_CHUNKS = TILE_COLS / 4;            // 20
    constexpr int TASKS_PER_T = TILE_ROWS * ROW_CHUNKS;  // 480
    for (int i = tid; i < 2 * TASKS_PER_T; i += 256) {
        int t   = i / TASKS_PER_T;
        int rem = i - t * TASKS_PER_T;
        int lr  = rem / ROW_CHUNKS;
        int lc4 = rem - lr * ROW_CHUNKS;
        int rg = tr0 + lr;
        int cg = tc0 + lc4 * 4;
        if ((unsigned)rg < (unsigned)H && (unsigned)cg < (unsigned)W) {
            const float* src = (t ? Bb : Ab) + rg * W + cg;
            float4 fx = *(const float4*)(src);
            float4 fy = *(const float4*)(src + HW);
            float* dst = &lds[t * TILE_FLOATS + (lr * LSTRIDE + lc4 * 4) * 2];
            *(float4*)(dst)     = make_float4(fx.x, fy.x, fx.y, fy.y);
            *(float4*)(dst + 4) = make_float4(fx.z, fy.z, fx.w, fy.w);
        }
    }
    __syncthreads();

    const float* ldsA = lds;
    const float* ldsB = lds + TILE_FLOATS;
    int x  = bx0 + lane;
    int yb = by0 + wv * 4;        // 4 consecutive rows per thread
    int lxc = lane + C_HALO;
    float xf = (float)x;

    // centers: one ds_read_b64 per tensor per pixel (2-way aliasing = free)
    v2f aC[4], bC[4];
    #pragma unroll
    for (int p = 0; p < 4; ++p) {
        int co = (wv * 4 + p + R_HALO) * LSTRIDE + lxc;
        aC[p] = *(const v2f*)(ldsA + 2 * co);
        bC[p] = *(const v2f*)(ldsB + 2 * co);
    }

    // ---- depth-2 software pipeline: issue(p) overlaps eval(p-1) ----------
    Pix st[4];                    // fully unrolled -> registers (const idx)
    float s = 0.0f;
    #pragma unroll
    for (int q = 0; q < 5; ++q) {
        if (q < 4) {
            const int p = q;
            float yf = (float)(yb + p);
            v2f xy = (v2f){xf, yf};
            dir_meta(bC[p], xy, st[p].m1);   // ABA: outer flow B, gather A
            dir_meta(aC[p], xy, st[p].m2);   // BAB: outer flow A, gather B
            gather_issue(ldsA, st[p].m1, tc0, tr0, st[p].e1,
                         st[p].u10, st[p].v10, st[p].u11, st[p].v11);
            gather_issue(ldsB, st[p].m2, tc0, tr0, st[p].e2,
                         st[p].u20, st[p].v20, st[p].u21, st[p].v21);
        }
        if (q >= 1) {
            const int p = q - 1;
            float yf = (float)(yb + p);
            if (!st[p].e1)        // divergent-rare: execz-skip on interior waves
                gather_fallback(Ab, st[p].m1,
                                st[p].u10, st[p].v10, st[p].u11, st[p].v11);
            if (!st[p].e2)
                gather_fallback(Bb, st[p].m2,
                                st[p].u20, st[p].v20, st[p].u21, st[p].v21);
            bool ok = fast_ok(st[p].m1.f0, st[p].u10, st[p].v10, st[p].u11, st[p].v11)
                    & fast_ok(st[p].m2.f0, st[p].u20, st[p].v20, st[p].u21, st[p].v21);
            if (__all(ok)) {
                s += fast_eval(st[p].m1, st[p].u10, st[p].v10, st[p].u11, st[p].v11, bC[p]);
                s += fast_eval(st[p].m2, st[p].u20, st[p].v20, st[p].u21, st[p].v21, aC[p]);
            } else {
                s += dir_eval(st[p].m1, st[p].u10, st[p].v10, st[p].u11, st[p].v11, xf, yf);
                s += dir_eval(st[p].m2, st[p].u20, st[p].v20, st[p].u21, st[p].v21, xf, yf);
            }
        }
    }

    // wave(64) shuffle reduce -> LDS -> one value per block
    #pragma unroll
    for (int o = 32; o > 0; o >>= 1) s += __shfl_down(s, o, 64);
    if (lane == 0) wsum[wv] = s;
    __syncthreads();
    if (tid == 0) {
        float tsum = wsum[0] + wsum[1] + wsum[2] + wsum[3];
        if (use_ws) {
            int bid = (blockIdx.z * gridDim.y + blockIdx.y) * gridDim.x + blockIdx.x;
            ws[bid] = tsum;                      // plain store, no atomics
        } else {
            atomicAdd(out, tsum * (1.0f / ((float)N * (float)H * (float)W)));
        }
    }
}

__global__ __launch_bounds__(256)
void reduce_kernel(const float* __restrict__ ws, float* __restrict__ out) {
    float s = 0.0f;
    for (int i = threadIdx.x; i < NBLOCKS / 4; i += 256) {   // float4: 9 iters
        float4 v = *(const float4*)(ws + 4 * i);
        s += (v.x + v.y) + (v.z + v.w);
    }
    #pragma unroll
    for (int o = 32; o > 0; o >>= 1) s += __shfl_down(s, o, 64);
    __shared__ float wsum[4];
    int lane = threadIdx.x & 63, wv = threadIdx.x >> 6;
    if (lane == 0) wsum[wv] = s;
    __syncthreads();
    if (threadIdx.x == 0) {
        float t = wsum[0] + wsum[1] + wsum[2] + wsum[3];
        out[0] = t * (1.0f / ((float)N * (float)H * (float)W));
    }
}

extern "C" void kernel_launch(void* const* d_in, const int* in_sizes, int n_in,
                              void* d_out, int out_size, void* d_ws, size_t ws_size,
                              hipStream_t stream) {
    const float* A = (const float*)d_in[0];   // UV_AtoB [16,2,768,768]
    const float* B = (const float*)d_in[1];   // UV_BtoA [16,2,768,768]
    float* out = (float*)d_out;               // scalar fp32
    float* ws  = (float*)d_ws;

    int use_ws = (ws_size >= NBLOCKS * sizeof(float)) ? 1 : 0;
    if (!use_ws) hipMemsetAsync(out, 0, sizeof(float), stream);

    dim3 grid(NBLK_X, NBLK_Y, N);             // (12, 48, 16) = 9216 blocks
    cycle_loss_kernel<<<grid, 256, 0, stream>>>(A, B, ws, out, use_ws);
    if (use_ws) reduce_kernel<<<1, 256, 0, stream>>>(ws, out);
}

// Round 3
// 213.047 us; speedup vs baseline: 1.0635x; 1.0360x over previous
//
#include <hip/hip_runtime.h>

// Problem constants (from reference setup_inputs). Note W == H == 768 -> all
// x/y scales and centers coincide, so packed (x,y) math shares constants.
constexpr int N = 16, H = 768, W = 768;
constexpr int HW = H * W;
constexpr float EPS2 = 1.0e-6f;            // EPS^2, EPS = 0.001
constexpr float INV = 1.0f / 767.0f;       // 1/(W-1) == 1/(H-1)
constexpr float WM1 = 767.0f, WM2 = 766.0f, HM1 = 767.0f;
constexpr float CHALF  = 383.5f;           // (W-1)/2 : |c-383.5|<=383.5 <=> c in [0,767]
constexpr float CHALFI = 383.0f;           // (W-2)/2 : |c-383|  <=383   <=> c in [0,766]

// Round-0 geometry (proven 92.5us) + LSTRIDE pad 80->84 (rows 8 banks apart).
// LDS = 2*24*84*2*4 + 16 = 32272 -> 64x512B granules = 32768B -> 5 blocks/CU
// x 4 waves = 20 waves/CU cap (same as round-0).
constexpr int TILE_COLS = 80;              // staged (real) cols: [bx0-8, bx0+72)
constexpr int TILE_ROWS = 24;              // staged rows: [by0-4, by0+20)
constexpr int C_HALO = 8;
constexpr int R_HALO = 4;
constexpr int LSTRIDE = 84;                // padded leading dim (pixels)
constexpr int TILE_FLOATS = TILE_ROWS * LSTRIDE * 2;  // 4032 floats per tensor
constexpr int MAXPIX = TILE_ROWS * LSTRIDE - 2;       // clamp for ld_quad
constexpr int NBLK_X = W / 64, NBLK_Y = H / 16;       // 12, 48
constexpr int NBLOCKS = NBLK_X * NBLK_Y * N;          // 9216

// packed-fp32 pair: arithmetic on this type emits v_pk_{add,mul,fma}_f32
typedef float v2f __attribute__((ext_vector_type(2)));
// 8-byte vector with 4-byte alignment promise (planar global fallback)
typedef float float2a __attribute__((ext_vector_type(2), aligned(4)));

struct DirMeta { v2f g; v2f f0; };

__device__ __forceinline__ void dir_meta(v2f flow, v2f xy, DirMeta& m) {
    m.g = xy + flow;                                   // 1 pk_add
    m.f0 = (v2f){floorf(m.g.x), floorf(m.g.y)};
}

// ---------- fast path ------------------------------------------------------
// Combined eligibility test for BOTH directions: bounds are identical, so the
// 8 per-corner |.| values and the 4 outer-floor |.| values share one max-tree
// (v_max3 fusion) and 3 compares total (was 8 compares + 2x and-chains).
// Eligible iff outer floor in [0,W-2]x[0,H-2] AND all 4 inner sample coords
// in [0,W-1]x[0,H-1] (then every validity mask is 1 and bilinear of the
// linear grid is the identity).
__device__ __forceinline__ bool fast_ok2(v2f f01, v2f u10, v2f v10, v2f u11, v2f v11,
                                         v2f f02, v2f u20, v2f v20, v2f u21, v2f v21) {
    v2f ca  = f01 - CHALF, cb  = f02 - CHALF;     // pk
    v2f ca1 = ca + 1.0f,   cb1 = cb + 1.0f;       // pk
    v2f da00 = ca  + u10, da11 = ca1 + v11;       // pk corners (0,0),(1,1)
    v2f db00 = cb  + u20, db11 = cb1 + v21;
    float da01x = ca1.x + v10.x, da01y = ca.y  + v10.y;   // (1,0)
    float da10x = ca.x  + u11.x, da10y = ca1.y + u11.y;   // (0,1)
    float db01x = cb1.x + v20.x, db01y = cb.y  + v20.y;
    float db10x = cb.x  + u21.x, db10y = cb1.y + u21.y;
    float xm = fmaxf(fmaxf(fabsf(da00.x), fabsf(da01x)),
                     fmaxf(fabsf(da10x), fabsf(da11.x)));
    xm = fmaxf(xm, fmaxf(fmaxf(fabsf(db00.x), fabsf(db01x)),
                         fmaxf(fabsf(db10x), fabsf(db11.x))));
    float ym = fmaxf(fmaxf(fabsf(da00.y), fabsf(da01y)),
                     fmaxf(fabsf(da10y), fabsf(da11.y)));
    ym = fmaxf(ym, fmaxf(fmaxf(fabsf(db00.y), fabsf(db01y)),
                         fmaxf(fabsf(db10y), fabsf(db11.y))));
    v2f ta = ca + 0.5f, tb = cb + 0.5f;           // pk: f0 - 383
    float tm = fmaxf(fmaxf(fabsf(ta.x), fabsf(ta.y)),
                     fmaxf(fabsf(tb.x), fabsf(tb.y)));
    return (xm <= CHALF) & (ym <= CHALF) & (tm <= CHALFI);
}

// All-valid residual (bilerp of flow1, identity inner warp):
__device__ __forceinline__ float fast_eval(const DirMeta& m,
                                           v2f u0, v2f v0, v2f u1, v2f v1,
                                           v2f cen) {
    v2f w = m.g - m.f0;                       // (wx1, wy1), pk
    v2f wx = (v2f){w.x, w.x};
    v2f wy = (v2f){w.y, w.y};
    v2f ft = u0 + wx * (v0 - u0);             // pk_sub + pk_fma
    v2f fb = u1 + wx * (v1 - u1);
    v2f fv = ft + wy * (fb - ft);
    v2f r = (cen + fv) * INV;                 // pk_add + pk_mul
    return sqrtf(fmaf(r.x, r.x, fmaf(r.y, r.y, EPS2)));
}

// ---------- general (border / wild-flow) path (verified rounds 4-7) --------
__device__ __forceinline__ float2 wg(float fx, float fy, float xi, float yi) {
    float gx = xi + fx, gy = yi + fy;
    float x0 = floorf(gx), y0 = floorf(gy);
    float wx1 = gx - x0, wx0 = 1.0f - wx1;
    float wy1 = gy - y0, wy0 = 1.0f - wy1;
    float vx0 = (x0 >= 0.0f  && x0 <= WM1)        ? 1.0f : 0.0f;
    float vx1 = (x0 >= -1.0f && x0 <= WM1 - 1.0f) ? 1.0f : 0.0f;
    float vy0 = (y0 >= 0.0f  && y0 <= HM1)        ? 1.0f : 0.0f;
    float vy1 = (y0 >= -1.0f && y0 <= HM1 - 1.0f) ? 1.0f : 0.0f;
    float ax = wx0 * vx0, bx = wx1 * vx1, sx = ax + bx;
    float ay = wy0 * vy0, by = wy1 * vy1, sy = ay + by;
    float ms = sx * sy;
    float kx = (ms >= 0.9999f) ? INV : 0.0f;
    float ky = (ms >= 0.9999f) ? INV : 0.0f;
    float2 r;
    r.x = fmaf(sx, x0, bx) * sy * kx;
    r.y = fmaf(sy, y0, by) * sx * ky;
    return r;
}

__device__ __forceinline__ float dir_eval(const DirMeta& m,
                                          v2f u0, v2f v0, v2f u1, v2f v1,
                                          float xf, float yf) {
    float x0f = m.f0.x, y0f = m.f0.y;
    float wx1 = m.g.x - x0f, wx0 = 1.0f - wx1;
    float wy1 = m.g.y - y0f, wy0 = 1.0f - wy1;
    float x1f = x0f + 1.0f, y1f = y0f + 1.0f;
    float vx0 = (x0f >= 0.0f && x0f <= WM1) ? 1.0f : 0.0f;
    float vx1 = (x1f >= 0.0f && x1f <= WM1) ? 1.0f : 0.0f;
    float vy0 = (y0f >= 0.0f && y0f <= HM1) ? 1.0f : 0.0f;
    float vy1 = (y1f >= 0.0f && y1f <= HM1) ? 1.0f : 0.0f;
    float axw = wx0 * vx0, bxw = wx1 * vx1;
    float ayw = wy0 * vy0, byw = wy1 * vy1;
    float sxw = axw + bxw, syw = ayw + byw;
    float msum = sxw * syw;

    // gathered pair is at base xb = clamp(x0,0,W-2): select col within pair
    bool selA = (x0f >= WM1);
    bool selB = (x0f >= 0.0f);
    float fx00 = selA ? v0.x : u0.x;
    float fx01 = selB ? v0.x : u0.x;
    float fy00 = selA ? v0.y : u0.y;
    float fy01 = selB ? v0.y : u0.y;
    float fx10 = selA ? v1.x : u1.x;
    float fx11 = selB ? v1.x : u1.x;
    float fy10 = selA ? v1.y : u1.y;
    float fy11 = selB ? v1.y : u1.y;

    float x0c = fminf(fmaxf(x0f, 0.0f), WM1);
    float x1c = fminf(fmaxf(x1f, 0.0f), WM1);
    float y0c = fminf(fmaxf(y0f, 0.0f), HM1);
    float y1c = fminf(fmaxf(y1f, 0.0f), HM1);

    float2 m00 = wg(fx00, fy00, x0c, y0c);
    float2 m01 = wg(fx01, fy01, x1c, y0c);
    float2 m10 = wg(fx10, fy10, x0c, y1c);
    float2 m11 = wg(fx11, fy11, x1c, y1c);

    float w00 = axw * ayw, w10 = bxw * ayw, w01 = axw * byw, w11 = bxw * byw;
    float mx = w00 * m00.x + w10 * m01.x + w01 * m10.x + w11 * m11.x;
    float my = w00 * m00.y + w10 * m01.y + w01 * m10.y + w11 * m11.y;
    float keep = (msum >= 0.9999f) ? 1.0f : 0.0f;
    mx *= keep; my *= keep;

    float dx = xf * INV - mx;
    float dy = yf * INV - my;
    return sqrtf(fmaf(dx, dx, fmaf(dy, dy, EPS2)));
}

// Pixel pair (pix, pix+1) from interleaved tile: two adjacent 8B reads at one
// base -> fuses to ds_read2_b64.
__device__ __forceinline__ void ld_quad(const float* t, int pix, v2f& u, v2f& v) {
    u = *(const v2f*)(t + 2 * pix);
    v = *(const v2f*)(t + 2 * pix + 2);
}

// Issue: UNCONDITIONAL clamped LDS gather at med3-clamped image coords (the
// clamped coords are the dir_eval contract). OOB-of-tile indices wrap to huge
// unsigned -> min-clamp to MAXPIX (uniform address, broadcast = free).
// Ineligible lanes' garbage is overwritten by gather_fallback before use.
__device__ __forceinline__ void gather_issue(const float* tile, const DirMeta& m,
                                             int tc0, int tr0, bool& e,
                                             v2f& u0, v2f& v0, v2f& u1, v2f& v1) {
    int xb = (int)fminf(fmaxf(m.f0.x, 0.0f), WM2);       // med3 + cvt
    int y0 = (int)fminf(fmaxf(m.f0.y, 0.0f), HM1);
    int y1 = (int)fminf(fmaxf(m.f0.y + 1.0f, 0.0f), HM1); // NOT y0+1: y0f=-1 case
    int xl = xb - tc0, yl0 = y0 - tr0, yl1 = y1 - tr0;
    e = ((unsigned)xl <= (unsigned)(TILE_COLS - 2))
      & ((unsigned)yl0 < (unsigned)TILE_ROWS)
      & ((unsigned)yl1 < (unsigned)TILE_ROWS);
    unsigned p0 = min((unsigned)(yl0 * LSTRIDE + xl), (unsigned)MAXPIX);
    unsigned p1 = min((unsigned)(yl1 * LSTRIDE + xl), (unsigned)MAXPIX);
    ld_quad(tile, (int)p0, u0, v0);
    ld_quad(tile, (int)p1, u1, v1);
}

// Rare path: per-lane global reload (border / wild flow), planar layout.
__device__ __forceinline__ void gather_fallback(const float* base, const DirMeta& m,
                                                v2f& u0, v2f& v0, v2f& u1, v2f& v1) {
    int xb = (int)fminf(fmaxf(m.f0.x, 0.0f), WM2);
    int y0 = (int)fminf(fmaxf(m.f0.y, 0.0f), HM1);
    int y1 = (int)fminf(fmaxf(m.f0.y + 1.0f, 0.0f), HM1);
    int o0 = y0 * W + xb, o1 = y1 * W + xb;
    float2a rx0 = *(const float2a*)(base + o0);
    float2a ry0 = *(const float2a*)(base + HW + o0);
    float2a rx1 = *(const float2a*)(base + o1);
    float2a ry1 = *(const float2a*)(base + HW + o1);
    u0 = (v2f){rx0.x, ry0.x}; v0 = (v2f){rx0.y, ry0.y};
    u1 = (v2f){rx1.x, ry1.x}; v1 = (v2f){rx1.y, ry1.y};
}

// ---- spill-proof pipeline stages: macro-generated SCALAR locals only ------
#define DECL_STAGE(P)                                                          \
    DirMeta m1_##P, m2_##P; bool e1_##P, e2_##P;                               \
    v2f u10_##P, v10_##P, u11_##P, v11_##P, u20_##P, v20_##P, u21_##P, v21_##P;

#define ISSUE(P) {                                                             \
    v2f xy = (v2f){xf, (float)(yb + P)};                                       \
    dir_meta(bC[P], xy, m1_##P);   /* ABA: outer flow B, gather A */           \
    dir_meta(aC[P], xy, m2_##P);   /* BAB: outer flow A, gather B */           \
    gather_issue(ldsA, m1_##P, tc0, tr0, e1_##P,                               \
                 u10_##P, v10_##P, u11_##P, v11_##P);                          \
    gather_issue(ldsB, m2_##P, tc0, tr0, e2_##P,                               \
                 u20_##P, v20_##P, u21_##P, v21_##P); }

#define EVAL(P) {                                                              \
    float yf = (float)(yb + P);                                                \
    if (!__all(e1_##P & e2_##P)) {     /* wave-uniform guard, usually skip */  \
        if (!e1_##P) gather_fallback(Ab, m1_##P,                               \
                                     u10_##P, v10_##P, u11_##P, v11_##P);      \
        if (!e2_##P) gather_fallback(Bb, m2_##P,                               \
                                     u20_##P, v20_##P, u21_##P, v21_##P);      \
    }                                                                          \
    bool ok = fast_ok2(m1_##P.f0, u10_##P, v10_##P, u11_##P, v11_##P,          \
                       m2_##P.f0, u20_##P, v20_##P, u21_##P, v21_##P);         \
    if (__all(ok)) {                                                           \
        s += fast_eval(m1_##P, u10_##P, v10_##P, u11_##P, v11_##P, bC[P]);     \
        s += fast_eval(m2_##P, u20_##P, v20_##P, u21_##P, v21_##P, aC[P]);     \
    } else {                                                                   \
        s += dir_eval(m1_##P, u10_##P, v10_##P, u11_##P, v11_##P, xf, yf);     \
        s += dir_eval(m2_##P, u20_##P, v20_##P, u21_##P, v21_##P, xf, yf);     \
    } }

__global__ __launch_bounds__(256, 4)
void cycle_loss_kernel(const float* __restrict__ A,   // UV_AtoB
                       const float* __restrict__ B,   // UV_BtoA
                       float* __restrict__ ws,
                       float* __restrict__ out,
                       int use_ws) {
    __shared__ float lds[2 * TILE_FLOATS];   // [0]=A tile, [TILE_FLOATS]=B tile
    __shared__ float wsum[4];

    int tid  = threadIdx.x;
    int lane = tid & 63;
    int wv   = tid >> 6;
    int bx0 = blockIdx.x * 64;
    int by0 = blockIdx.y * 16;
    int b   = blockIdx.z;
    const float* Ab = A + (size_t)b * 2 * HW;
    const float* Bb = B + (size_t)b * 2 * HW;
    int tc0 = bx0 - C_HALO;    // 16B-aligned
    int tr0 = by0 - R_HALO;

    // ---- stage both tensors as interleaved {fx,fy} tiles (round-0) -------
    constexpr int ROW_CHUNKS = TILE_COLS / 4;            // 20
    constexpr int TASKS_PER_T = TILE_ROWS * ROW_CHUNKS;  // 480
    for (int i = tid; i < 2 * TASKS_PER_T; i += 256) {
        int t   = i / TASKS_PER_T;
        int rem = i - t * TASKS_PER_T;
        int lr  = rem / ROW_CHUNKS;
        int lc4 = rem - lr * ROW_CHUNKS;
        int rg = tr0 + lr;
        int cg = tc0 + lc4 * 4;
        if ((unsigned)rg < (unsigned)H && (unsigned)cg < (unsigned)W) {
            const float* src = (t ? Bb : Ab) + rg * W + cg;
            float4 fx = *(const float4*)(src);
            float4 fy = *(const float4*)(src + HW);
            float* dst = &lds[t * TILE_FLOATS + (lr * LSTRIDE + lc4 * 4) * 2];
            *(float4*)(dst)     = make_float4(fx.x, fy.x, fx.y, fy.y);
            *(float4*)(dst + 4) = make_float4(fx.z, fy.z, fx.w, fy.w);
        }
    }
    __syncthreads();

    const float* ldsA = lds;
    const float* ldsB = lds + TILE_FLOATS;
    int x  = bx0 + lane;
    int yb = by0 + wv * 4;        // 4 consecutive rows per thread
    int lxc = lane + C_HALO;
    float xf = (float)x;

    // centers: one ds_read_b64 per tensor per pixel (2-way aliasing = free)
    v2f aC[4], bC[4];
    #pragma unroll
    for (int p = 0; p < 4; ++p) {
        int co = (wv * 4 + p + R_HALO) * LSTRIDE + lxc;
        aC[p] = *(const v2f*)(ldsA + 2 * co);
        bC[p] = *(const v2f*)(ldsB + 2 * co);
    }

    // ---- depth-2 pipeline, hand-unrolled: issue(p+1) hides eval(p)'s waits
    float s = 0.0f;
    {
        DECL_STAGE(0) DECL_STAGE(1) DECL_STAGE(2) DECL_STAGE(3)
        ISSUE(0)
        ISSUE(1)
        EVAL(0)
        ISSUE(2)
        EVAL(1)
        ISSUE(3)
        EVAL(2)
        EVAL(3)
    }

    // wave(64) shuffle reduce -> LDS -> one value per block
    #pragma unroll
    for (int o = 32; o > 0; o >>= 1) s += __shfl_down(s, o, 64);
    if (lane == 0) wsum[wv] = s;
    __syncthreads();
    if (tid == 0) {
        float tsum = wsum[0] + wsum[1] + wsum[2] + wsum[3];
        if (use_ws) {
            int bid = (blockIdx.z * gridDim.y + blockIdx.y) * gridDim.x + blockIdx.x;
            ws[bid] = tsum;                      // plain store, no atomics
        } else {
            atomicAdd(out, tsum * (1.0f / ((float)N * (float)H * (float)W)));
        }
    }
}

__global__ __launch_bounds__(256)
void reduce_kernel(const float* __restrict__ ws, float* __restrict__ out) {
    float s = 0.0f;
    for (int i = threadIdx.x; i < NBLOCKS / 4; i += 256) {   // float4: 9 iters
        float4 v = *(const float4*)(ws + 4 * i);
        s += (v.x + v.y) + (v.z + v.w);
    }
    #pragma unroll
    for (int o = 32; o > 0; o >>= 1) s += __shfl_down(s, o, 64);
    __shared__ float wsum[4];
    int lane = threadIdx.x & 63, wv = threadIdx.x >> 6;
    if (lane == 0) wsum[wv] = s;
    __syncthreads();
    if (threadIdx.x == 0) {
        float t = wsum[0] + wsum[1] + wsum[2] + wsum[3];
        out[0] = t * (1.0f / ((float)N * (float)H * (float)W));
    }
}

extern "C" void kernel_launch(void* const* d_in, const int* in_sizes, int n_in,
                              void* d_out, int out_size, void* d_ws, size_t ws_size,
                              hipStream_t stream) {
    const float* A = (const float*)d_in[0];   // UV_AtoB [16,2,768,768]
    const float* B = (const float*)d_in[1];   // UV_BtoA [16,2,768,768]
    float* out = (float*)d_out;               // scalar fp32
    float* ws  = (float*)d_ws;

    int use_ws = (ws_size >= NBLOCKS * sizeof(float)) ? 1 : 0;
    if (!use_ws) hipMemsetAsync(out, 0, sizeof(float), stream);

    dim3 grid(NBLK_X, NBLK_Y, N);             // (12, 48, 16) = 9216 blocks
    cycle_loss_kernel<<<grid, 256, 0, stream>>>(A, B, ws, out, use_ws);
    if (use_ws) reduce_kernel<<<1, 256, 0, stream>>>(ws, out);
}

// Round 4
// 210.785 us; speedup vs baseline: 1.0749x; 1.0107x over previous
//
#include <hip/hip_runtime.h>

// Problem constants (from reference setup_inputs). Note W == H == 768 -> all
// x/y scales and centers coincide, so packed (x,y) math shares constants.
constexpr int N = 16, H = 768, W = 768;
constexpr int HW = H * W;
constexpr float EPS2 = 1.0e-6f;            // EPS^2, EPS = 0.001
constexpr float INV = 1.0f / 767.0f;       // 1/(W-1) == 1/(H-1)
constexpr float WM1 = 767.0f, WM2 = 766.0f, HM1 = 767.0f;
constexpr float CHALF  = 383.5f;           // (W-1)/2 : |c-383.5|<=383.5 <=> c in [0,767]
constexpr float CHALFI = 383.0f;           // (W-2)/2 : |c-383|  <=383   <=> c in [0,766]

// Round-4 geometry: 64 cols x 12 rows output per 256-thread block (3 px/thr),
// halo 8 cols / 4 rows -> staged tile 80x20. LDS = 2*20*84*2*4 + 16 = 26896
// -> 53x512B granules = 27136B -> 6 blocks/CU x 4 waves = 24 waves/CU cap
// (round-0 was 5x4=20). Structure is round-0's proven branchy gather (VGPR 48,
// zero scratch) -- rounds 1-3 showed source-level pipelining just makes the
// scheduler hoist loads and spill (WRITE_SIZE canary 37-74MB).
constexpr int TILE_COLS = 80;              // staged (real) cols: [bx0-8, bx0+72)
constexpr int TILE_ROWS = 20;              // staged rows: [by0-4, by0+16)
constexpr int OUT_ROWS = 12;               // output rows per block
constexpr int C_HALO = 8;
constexpr int R_HALO = 4;
constexpr int LSTRIDE = 84;                // padded: rows 8 banks apart (84*2 % 32 = 8)
constexpr int TILE_FLOATS = TILE_ROWS * LSTRIDE * 2;  // 3360 floats per tensor
constexpr int NBLK_X = W / 64, NBLK_Y = H / OUT_ROWS; // 12, 64
constexpr int NBLOCKS = NBLK_X * NBLK_Y * N;          // 12288

// packed-fp32 pair: arithmetic on this type emits v_pk_{add,mul,fma}_f32
typedef float v2f __attribute__((ext_vector_type(2)));
// 8-byte vector with 4-byte alignment promise (planar global fallback)
typedef float float2a __attribute__((ext_vector_type(2), aligned(4)));

struct DirMeta { v2f g; v2f f0; int xb, y0, y1; };

__device__ __forceinline__ void dir_meta(v2f flow, v2f xy, DirMeta& m) {
    m.g = xy + flow;                                   // 1 pk_add
    m.f0 = (v2f){floorf(m.g.x), floorf(m.g.y)};
    m.xb = (int)fminf(fmaxf(m.f0.x, 0.0f), WM2);       // med3 + cvt
    m.y0 = (int)fminf(fmaxf(m.f0.y, 0.0f), HM1);
    m.y1 = (int)fminf(fmaxf(m.f0.y + 1.0f, 0.0f), HM1); // NOT min(y0+1,..): y0f=-1 case
}

// ---------- fast path ------------------------------------------------------
// Combined eligibility for BOTH directions: bounds identical, so the 8
// per-corner |.| values and 4 outer-floor |.| values share one max-tree
// (v_max3 fusion) and 3 compares total (was 8 compares + 2 and-chains).
// Eligible iff outer floor in [0,W-2]x[0,H-2] AND all 4 inner sample coords
// in [0,W-1]x[0,H-1] (then every validity mask is 1 and bilinear of the
// linear grid is the identity). fabs() are free input modifiers.
__device__ __forceinline__ bool fast_ok2(v2f f01, v2f u10, v2f v10, v2f u11, v2f v11,
                                         v2f f02, v2f u20, v2f v20, v2f u21, v2f v21) {
    v2f ca  = f01 - CHALF, cb  = f02 - CHALF;     // pk
    v2f ca1 = ca + 1.0f,   cb1 = cb + 1.0f;       // pk
    v2f da00 = ca  + u10, da11 = ca1 + v11;       // pk corners (0,0),(1,1)
    v2f db00 = cb  + u20, db11 = cb1 + v21;
    float da01x = ca1.x + v10.x, da01y = ca.y  + v10.y;   // (1,0)
    float da10x = ca.x  + u11.x, da10y = ca1.y + u11.y;   // (0,1)
    float db01x = cb1.x + v20.x, db01y = cb.y  + v20.y;
    float db10x = cb.x  + u21.x, db10y = cb1.y + u21.y;
    float xm = fmaxf(fmaxf(fabsf(da00.x), fabsf(da01x)),
                     fmaxf(fabsf(da10x), fabsf(da11.x)));
    xm = fmaxf(xm, fmaxf(fmaxf(fabsf(db00.x), fabsf(db01x)),
                         fmaxf(fabsf(db10x), fabsf(db11.x))));
    float ym = fmaxf(fmaxf(fabsf(da00.y), fabsf(da01y)),
                     fmaxf(fabsf(da10y), fabsf(da11.y)));
    ym = fmaxf(ym, fmaxf(fmaxf(fabsf(db00.y), fabsf(db01y)),
                         fmaxf(fabsf(db10y), fabsf(db11.y))));
    v2f ta = ca + 0.5f, tb = cb + 0.5f;           // pk: f0 - 383
    float tm = fmaxf(fmaxf(fabsf(ta.x), fabsf(ta.y)),
                     fmaxf(fabsf(tb.x), fabsf(tb.y)));
    return (xm <= CHALF) & (ym <= CHALF) & (tm <= CHALFI);
}

// All-valid residual (bilerp of flow1, identity inner warp):
__device__ __forceinline__ float fast_eval(const DirMeta& m,
                                           v2f u0, v2f v0, v2f u1, v2f v1,
                                           v2f cen) {
    v2f w = m.g - m.f0;                       // (wx1, wy1), pk
    v2f wx = (v2f){w.x, w.x};
    v2f wy = (v2f){w.y, w.y};
    v2f ft = u0 + wx * (v0 - u0);             // pk_sub + pk_fma
    v2f fb = u1 + wx * (v1 - u1);
    v2f fv = ft + wy * (fb - ft);
    v2f r = (cen + fv) * INV;                 // pk_add + pk_mul
    return sqrtf(fmaf(r.x, r.x, fmaf(r.y, r.y, EPS2)));
}

// ---------- general (border / wild-flow) path (verified rounds 4-7) --------
__device__ __forceinline__ float2 wg(float fx, float fy, float xi, float yi) {
    float gx = xi + fx, gy = yi + fy;
    float x0 = floorf(gx), y0 = floorf(gy);
    float wx1 = gx - x0, wx0 = 1.0f - wx1;
    float wy1 = gy - y0, wy0 = 1.0f - wy1;
    float vx0 = (x0 >= 0.0f  && x0 <= WM1)        ? 1.0f : 0.0f;
    float vx1 = (x0 >= -1.0f && x0 <= WM1 - 1.0f) ? 1.0f : 0.0f;
    float vy0 = (y0 >= 0.0f  && y0 <= HM1)        ? 1.0f : 0.0f;
    float vy1 = (y0 >= -1.0f && y0 <= HM1 - 1.0f) ? 1.0f : 0.0f;
    float ax = wx0 * vx0, bx = wx1 * vx1, sx = ax + bx;
    float ay = wy0 * vy0, by = wy1 * vy1, sy = ay + by;
    float ms = sx * sy;
    float kx = (ms >= 0.9999f) ? INV : 0.0f;
    float ky = (ms >= 0.9999f) ? INV : 0.0f;
    float2 r;
    r.x = fmaf(sx, x0, bx) * sy * kx;
    r.y = fmaf(sy, y0, by) * sx * ky;
    return r;
}

__device__ __forceinline__ float dir_eval(const DirMeta& m,
                                          v2f u0, v2f v0, v2f u1, v2f v1,
                                          float xf, float yf) {
    float x0f = m.f0.x, y0f = m.f0.y;
    float wx1 = m.g.x - x0f, wx0 = 1.0f - wx1;
    float wy1 = m.g.y - y0f, wy0 = 1.0f - wy1;
    float x1f = x0f + 1.0f, y1f = y0f + 1.0f;
    float vx0 = (x0f >= 0.0f && x0f <= WM1) ? 1.0f : 0.0f;
    float vx1 = (x1f >= 0.0f && x1f <= WM1) ? 1.0f : 0.0f;
    float vy0 = (y0f >= 0.0f && y0f <= HM1) ? 1.0f : 0.0f;
    float vy1 = (y1f >= 0.0f && y1f <= HM1) ? 1.0f : 0.0f;
    float axw = wx0 * vx0, bxw = wx1 * vx1;
    float ayw = wy0 * vy0, byw = wy1 * vy1;
    float sxw = axw + bxw, syw = ayw + byw;
    float msum = sxw * syw;

    // gathered pair is at base xb = clamp(x0,0,W-2): select col within pair
    bool selA = (x0f >= WM1);
    bool selB = (x0f >= 0.0f);
    float fx00 = selA ? v0.x : u0.x;
    float fx01 = selB ? v0.x : u0.x;
    float fy00 = selA ? v0.y : u0.y;
    float fy01 = selB ? v0.y : u0.y;
    float fx10 = selA ? v1.x : u1.x;
    float fx11 = selB ? v1.x : u1.x;
    float fy10 = selA ? v1.y : u1.y;
    float fy11 = selB ? v1.y : u1.y;

    float x0c = fminf(fmaxf(x0f, 0.0f), WM1);
    float x1c = fminf(fmaxf(x1f, 0.0f), WM1);
    float y0c = fminf(fmaxf(y0f, 0.0f), HM1);
    float y1c = fminf(fmaxf(y1f, 0.0f), HM1);

    float2 m00 = wg(fx00, fy00, x0c, y0c);
    float2 m01 = wg(fx01, fy01, x1c, y0c);
    float2 m10 = wg(fx10, fy10, x0c, y1c);
    float2 m11 = wg(fx11, fy11, x1c, y1c);

    float w00 = axw * ayw, w10 = bxw * ayw, w01 = axw * byw, w11 = bxw * byw;
    float mx = w00 * m00.x + w10 * m01.x + w01 * m10.x + w11 * m11.x;
    float my = w00 * m00.y + w10 * m01.y + w01 * m10.y + w11 * m11.y;
    float keep = (msum >= 0.9999f) ? 1.0f : 0.0f;
    mx *= keep; my *= keep;

    float dx = xf * INV - mx;
    float dy = yf * INV - my;
    return sqrtf(fmaf(dx, dx, fmaf(dy, dy, EPS2)));
}

// Pixel pair (pix, pix+1) from interleaved tile: two adjacent 8B reads at one
// base -> fuses to ds_read2_b64.
__device__ __forceinline__ void ld_quad(const float* t, int pix, v2f& u, v2f& v) {
    u = *(const v2f*)(t + 2 * pix);
    v = *(const v2f*)(t + 2 * pix + 2);
}

__global__ __launch_bounds__(256, 6)
void cycle_loss_kernel(const float* __restrict__ A,   // UV_AtoB
                       const float* __restrict__ B,   // UV_BtoA
                       float* __restrict__ ws,
                       float* __restrict__ out,
                       int use_ws) {
    __shared__ float lds[2 * TILE_FLOATS];   // [0]=A tile, [TILE_FLOATS]=B tile
    __shared__ float wsum[4];

    int tid  = threadIdx.x;
    int lane = tid & 63;
    int wv   = tid >> 6;
    int bx0 = blockIdx.x * 64;
    int by0 = blockIdx.y * OUT_ROWS;
    int b   = blockIdx.z;
    const float* Ab = A + (size_t)b * 2 * HW;
    const float* Bb = B + (size_t)b * 2 * HW;
    int tc0 = bx0 - C_HALO;    // 16B-aligned
    int tr0 = by0 - R_HALO;

    // ---- stage both tensors as interleaved {fx,fy} tiles (round-0) -------
    constexpr int ROW_CHUNKS = TILE_COLS / 4;            // 20
    constexpr int TASKS_PER_T = TILE_ROWS * ROW_CHUNKS;  // 400
    for (int i = tid; i < 2 * TASKS_PER_T; i += 256) {
        int t   = i / TASKS_PER_T;
        int rem = i - t * TASKS_PER_T;
        int lr  = rem / ROW_CHUNKS;
        int lc4 = rem - lr * ROW_CHUNKS;
        int rg = tr0 + lr;
        int cg = tc0 + lc4 * 4;
        if ((unsigned)rg < (unsigned)H && (unsigned)cg < (unsigned)W) {
            const float* src = (t ? Bb : Ab) + rg * W + cg;
            float4 fx = *(const float4*)(src);
            float4 fy = *(const float4*)(src + HW);
            float* dst = &lds[t * TILE_FLOATS + (lr * LSTRIDE + lc4 * 4) * 2];
            *(float4*)(dst)     = make_float4(fx.x, fy.x, fx.y, fy.y);
            *(float4*)(dst + 4) = make_float4(fx.z, fy.z, fx.w, fy.w);
        }
    }
    __syncthreads();

    const float* ldsA = lds;
    const float* ldsB = lds + TILE_FLOATS;
    int x  = bx0 + lane;
    int yb = by0 + wv * 3;        // 3 consecutive rows per thread
    int lxc = lane + C_HALO;
    float xf = (float)x;

    // centers: one ds_read_b64 per tensor per pixel (2-way aliasing = free)
    v2f aC[3], bC[3];
    #pragma unroll
    for (int p = 0; p < 3; ++p) {
        int co = (wv * 3 + p + R_HALO) * LSTRIDE + lxc;
        aC[p] = *(const v2f*)(ldsA + 2 * co);
        bC[p] = *(const v2f*)(ldsB + 2 * co);
    }

    float s = 0.0f;
    #pragma unroll
    for (int p = 0; p < 3; ++p) {
        float yf = (float)(yb + p);
        v2f xy = (v2f){xf, yf};
        DirMeta m1, m2;
        dir_meta(bC[p], xy, m1);   // ABA: outer flow B, gather A
        dir_meta(aC[p], xy, m2);   // BAB: outer flow A, gather B

        // tile-local coords + eligibility (unsigned trick)
        int x1l = m1.xb - tc0, y1l0 = m1.y0 - tr0, y1l1 = m1.y1 - tr0;
        int x2l = m2.xb - tc0, y2l0 = m2.y0 - tr0, y2l1 = m2.y1 - tr0;
        bool e1 = ((unsigned)x1l <= (unsigned)(TILE_COLS - 2))
                & ((unsigned)y1l0 < (unsigned)TILE_ROWS)
                & ((unsigned)y1l1 < (unsigned)TILE_ROWS);
        bool e2 = ((unsigned)x2l <= (unsigned)(TILE_COLS - 2))
                & ((unsigned)y2l0 < (unsigned)TILE_ROWS)
                & ((unsigned)y2l1 < (unsigned)TILE_ROWS);

        v2f u10, v10, u11, v11, u20, v20, u21, v21;
        if (__all(e1 & e2)) {
            ld_quad(ldsA, y1l0 * LSTRIDE + x1l, u10, v10);
            ld_quad(ldsA, y1l1 * LSTRIDE + x1l, u11, v11);
            ld_quad(ldsB, y2l0 * LSTRIDE + x2l, u20, v20);
            ld_quad(ldsB, y2l1 * LSTRIDE + x2l, u21, v21);
        } else {
            // rare: per-lane LDS/global select
            if (e1) {
                ld_quad(ldsA, y1l0 * LSTRIDE + x1l, u10, v10);
                ld_quad(ldsA, y1l1 * LSTRIDE + x1l, u11, v11);
            } else {
                int o0 = m1.y0 * W + m1.xb, o1 = m1.y1 * W + m1.xb;
                float2a rx0 = *(const float2a*)(Ab + o0);
                float2a ry0 = *(const float2a*)(Ab + HW + o0);
                float2a rx1 = *(const float2a*)(Ab + o1);
                float2a ry1 = *(const float2a*)(Ab + HW + o1);
                u10 = (v2f){rx0.x, ry0.x}; v10 = (v2f){rx0.y, ry0.y};
                u11 = (v2f){rx1.x, ry1.x}; v11 = (v2f){rx1.y, ry1.y};
            }
            if (e2) {
                ld_quad(ldsB, y2l0 * LSTRIDE + x2l, u20, v20);
                ld_quad(ldsB, y2l1 * LSTRIDE + x2l, u21, v21);
            } else {
                int o0 = m2.y0 * W + m2.xb, o1 = m2.y1 * W + m2.xb;
                float2a rx0 = *(const float2a*)(Bb + o0);
                float2a ry0 = *(const float2a*)(Bb + HW + o0);
                float2a rx1 = *(const float2a*)(Bb + o1);
                float2a ry1 = *(const float2a*)(Bb + HW + o1);
                u20 = (v2f){rx0.x, ry0.x}; v20 = (v2f){rx0.y, ry0.y};
                u21 = (v2f){rx1.x, ry1.x}; v21 = (v2f){rx1.y, ry1.y};
            }
        }

        bool ok = fast_ok2(m1.f0, u10, v10, u11, v11,
                           m2.f0, u20, v20, u21, v21);
        if (__all(ok)) {
            s += fast_eval(m1, u10, v10, u11, v11, bC[p]);
            s += fast_eval(m2, u20, v20, u21, v21, aC[p]);
        } else {
            s += dir_eval(m1, u10, v10, u11, v11, xf, yf);
            s += dir_eval(m2, u20, v20, u21, v21, xf, yf);
        }
    }

    // wave(64) shuffle reduce -> LDS -> one value per block
    #pragma unroll
    for (int o = 32; o > 0; o >>= 1) s += __shfl_down(s, o, 64);
    if (lane == 0) wsum[wv] = s;
    __syncthreads();
    if (tid == 0) {
        float tsum = wsum[0] + wsum[1] + wsum[2] + wsum[3];
        if (use_ws) {
            int bid = (blockIdx.z * gridDim.y + blockIdx.y) * gridDim.x + blockIdx.x;
            ws[bid] = tsum;                      // plain store, no atomics
        } else {
            atomicAdd(out, tsum * (1.0f / ((float)N * (float)H * (float)W)));
        }
    }
}

__global__ __launch_bounds__(256)
void reduce_kernel(const float* __restrict__ ws, float* __restrict__ out) {
    float s = 0.0f;
    for (int i = threadIdx.x; i < NBLOCKS / 4; i += 256) {   // float4: 12 iters
        float4 v = *(const float4*)(ws + 4 * i);
        s += (v.x + v.y) + (v.z + v.w);
    }
    #pragma unroll
    for (int o = 32; o > 0; o >>= 1) s += __shfl_down(s, o, 64);
    __shared__ float wsum[4];
    int lane = threadIdx.x & 63, wv = threadIdx.x >> 6;
    if (lane == 0) wsum[wv] = s;
    __syncthreads();
    if (threadIdx.x == 0) {
        float t = wsum[0] + wsum[1] + wsum[2] + wsum[3];
        out[0] = t * (1.0f / ((float)N * (float)H * (float)W));
    }
}

extern "C" void kernel_launch(void* const* d_in, const int* in_sizes, int n_in,
                              void* d_out, int out_size, void* d_ws, size_t ws_size,
                              hipStream_t stream) {
    const float* A = (const float*)d_in[0];   // UV_AtoB [16,2,768,768]
    const float* B = (const float*)d_in[1];   // UV_BtoA [16,2,768,768]
    float* out = (float*)d_out;               // scalar fp32
    float* ws  = (float*)d_ws;

    int use_ws = (ws_size >= NBLOCKS * sizeof(float)) ? 1 : 0;
    if (!use_ws) hipMemsetAsync(out, 0, sizeof(float), stream);

    dim3 grid(NBLK_X, NBLK_Y, N);             // (12, 64, 16) = 12288 blocks
    cycle_loss_kernel<<<grid, 256, 0, stream>>>(A, B, ws, out, use_ws);
    if (use_ws) reduce_kernel<<<1, 256, 0, stream>>>(ws, out);
}

// Round 5
// 205.217 us; speedup vs baseline: 1.1040x; 1.0271x over previous
//
#include <hip/hip_runtime.h>

// Problem constants (from reference setup_inputs). Note W == H == 768 -> all
// x/y scales and centers coincide, so packed (x,y) math shares constants.
constexpr int N = 16, H = 768, W = 768;
constexpr int HW = H * W;
constexpr float EPS2 = 1.0e-6f;            // EPS^2, EPS = 0.001
constexpr float INV = 1.0f / 767.0f;       // 1/(W-1) == 1/(H-1)
constexpr float WM1 = 767.0f, WM2 = 766.0f, HM1 = 767.0f;
constexpr float CHALF  = 383.5f;           // (W-1)/2 : |c-383.5|<=383.5 <=> c in [0,767]
constexpr float CHALFI = 383.0f;           // (W-2)/2 : |c-383|  <=383   <=> c in [0,766]

// Round-5: EXACT round-0 code body (per-direction fast_ok, plain
// __launch_bounds__(256), LSTRIDE=80, branchy gather -- the proven
// VGPR-48 / zero-scratch configuration) with ONE variable changed:
// tile geometry 64x16 -> 64x12 output (80x20 staged, 3 px/thread).
// LDS = 2*20*80*2*4 + 16 = 25616 -> 26112B rounded -> 6 blocks/CU x 4
// waves = 24 waves/CU occupancy cap (round-0 was 5x4=20).
// Rounds 3/4 post-mortem: fast_ok2 fusion and/or __launch_bounds__(.,6)
// caused a persistent 16B/thread scratch spill (WRITE_SIZE 37-50MB) --
// both reverted here; WRITE_SIZE is the canary.
constexpr int TILE_COLS = 80;              // staged cols: [bx0-8, bx0+72)
constexpr int TILE_ROWS = 20;              // staged rows: [by0-4, by0+16)
constexpr int OUT_ROWS = 12;               // output rows per block
constexpr int C_HALO = 8;
constexpr int R_HALO = 4;
constexpr int LSTRIDE = TILE_COLS;         // 80 (round-0 value)
constexpr int TILE_FLOATS = TILE_ROWS * LSTRIDE * 2;  // 3200 floats per tensor
constexpr int NBLK_X = W / 64, NBLK_Y = H / OUT_ROWS; // 12, 64
constexpr int NBLOCKS = NBLK_X * NBLK_Y * N;          // 12288

// packed-fp32 pair: arithmetic on this type emits v_pk_{add,mul,fma}_f32
typedef float v2f __attribute__((ext_vector_type(2)));
// 8-byte vector with 4-byte alignment promise (planar global fallback)
typedef float float2a __attribute__((ext_vector_type(2), aligned(4)));

struct DirMeta { v2f g; v2f f0; int xb, y0, y1; };

__device__ __forceinline__ void dir_meta(v2f flow, v2f xy, DirMeta& m) {
    m.g = xy + flow;                                   // 1 pk_add
    m.f0 = (v2f){floorf(m.g.x), floorf(m.g.y)};
    m.xb = (int)fminf(fmaxf(m.f0.x, 0.0f), WM2);       // med3 + cvt
    m.y0 = (int)fminf(fmaxf(m.f0.y, 0.0f), HM1);
    m.y1 = (int)fminf(fmaxf(m.f0.y + 1.0f, 0.0f), HM1); // NOT min(y0+1,..): y0f=-1 case
}

// ---------- fast path ------------------------------------------------------
// Quads: u0={fx,fy}@(y0,xb), v0=@(y0,xb+1), u1=@(y1,xb), v1=@(y1,xb+1).
// Eligible iff outer floor in [0,W-2]x[0,H-2] AND all 4 inner sample coords
// in [0,W-1]x[0,H-1] (then every validity mask is 1 and bilinear of the
// linear grid is the identity). Centered-abs form: compares use free |x|
// input modifiers; max-trees fuse to v_max3; diagonal corners pack.
__device__ __forceinline__ bool fast_ok(v2f f0, v2f u0, v2f v0, v2f u1, v2f v1) {
    v2f c  = f0 - CHALF;          // pk
    v2f c1 = c + 1.0f;            // pk
    v2f d00 = c  + u0;            // pk: corner (+0,+0)
    v2f d11 = c1 + v1;            // pk: corner (+1,+1)
    float d01x = c1.x + v0.x, d01y = c.y  + v0.y;   // corner (+1,+0)
    float d10x = c.x  + u1.x, d10y = c1.y + u1.y;   // corner (+0,+1)
    float xm = fmaxf(fabsf(d00.x), fabsf(d01x));
    xm = fmaxf(xm, fmaxf(fabsf(d10x), fabsf(d11.x)));   // v_max3
    float ym = fmaxf(fabsf(d00.y), fabsf(d01y));
    ym = fmaxf(ym, fmaxf(fabsf(d10y), fabsf(d11.y)));
    v2f t = c + 0.5f;             // pk: f0 - 383
    return (xm <= CHALF) & (ym <= CHALF)
         & (fabsf(t.x) <= CHALFI) & (fabsf(t.y) <= CHALFI);
}

// All-valid residual (bilerp of flow1, identity inner warp):
__device__ __forceinline__ float fast_eval(const DirMeta& m,
                                           v2f u0, v2f v0, v2f u1, v2f v1,
                                           v2f cen) {
    v2f w = m.g - m.f0;                       // (wx1, wy1), pk
    v2f wx = (v2f){w.x, w.x};
    v2f wy = (v2f){w.y, w.y};
    v2f ft = u0 + wx * (v0 - u0);             // pk_sub + pk_fma
    v2f fb = u1 + wx * (v1 - u1);
    v2f fv = ft + wy * (fb - ft);
    v2f r = (cen + fv) * INV;                 // pk_add + pk_mul
    return sqrtf(fmaf(r.x, r.x, fmaf(r.y, r.y, EPS2)));
}

// ---------- general (border / wild-flow) path (verified rounds 4-7) --------
__device__ __forceinline__ float2 wg(float fx, float fy, float xi, float yi) {
    float gx = xi + fx, gy = yi + fy;
    float x0 = floorf(gx), y0 = floorf(gy);
    float wx1 = gx - x0, wx0 = 1.0f - wx1;
    float wy1 = gy - y0, wy0 = 1.0f - wy1;
    float vx0 = (x0 >= 0.0f  && x0 <= WM1)        ? 1.0f : 0.0f;
    float vx1 = (x0 >= -1.0f && x0 <= WM1 - 1.0f) ? 1.0f : 0.0f;
    float vy0 = (y0 >= 0.0f  && y0 <= HM1)        ? 1.0f : 0.0f;
    float vy1 = (y0 >= -1.0f && y0 <= HM1 - 1.0f) ? 1.0f : 0.0f;
    float ax = wx0 * vx0, bx = wx1 * vx1, sx = ax + bx;
    float ay = wy0 * vy0, by = wy1 * vy1, sy = ay + by;
    float ms = sx * sy;
    float kx = (ms >= 0.9999f) ? INV : 0.0f;
    float ky = (ms >= 0.9999f) ? INV : 0.0f;
    float2 r;
    r.x = fmaf(sx, x0, bx) * sy * kx;
    r.y = fmaf(sy, y0, by) * sx * ky;
    return r;
}

__device__ __forceinline__ float dir_eval(const DirMeta& m,
                                          v2f u0, v2f v0, v2f u1, v2f v1,
                                          float xf, float yf) {
    float x0f = m.f0.x, y0f = m.f0.y;
    float wx1 = m.g.x - x0f, wx0 = 1.0f - wx1;
    float wy1 = m.g.y - y0f, wy0 = 1.0f - wy1;
    float x1f = x0f + 1.0f, y1f = y0f + 1.0f;
    float vx0 = (x0f >= 0.0f && x0f <= WM1) ? 1.0f : 0.0f;
    float vx1 = (x1f >= 0.0f && x1f <= WM1) ? 1.0f : 0.0f;
    float vy0 = (y0f >= 0.0f && y0f <= HM1) ? 1.0f : 0.0f;
    float vy1 = (y1f >= 0.0f && y1f <= HM1) ? 1.0f : 0.0f;
    float axw = wx0 * vx0, bxw = wx1 * vx1;
    float ayw = wy0 * vy0, byw = wy1 * vy1;
    float sxw = axw + bxw, syw = ayw + byw;
    float msum = sxw * syw;

    // gathered pair is at base xb = clamp(x0,0,W-2): select col within pair
    bool selA = (x0f >= WM1);
    bool selB = (x0f >= 0.0f);
    float fx00 = selA ? v0.x : u0.x;
    float fx01 = selB ? v0.x : u0.x;
    float fy00 = selA ? v0.y : u0.y;
    float fy01 = selB ? v0.y : u0.y;
    float fx10 = selA ? v1.x : u1.x;
    float fx11 = selB ? v1.x : u1.x;
    float fy10 = selA ? v1.y : u1.y;
    float fy11 = selB ? v1.y : u1.y;

    float x0c = fminf(fmaxf(x0f, 0.0f), WM1);
    float x1c = fminf(fmaxf(x1f, 0.0f), WM1);
    float y0c = fminf(fmaxf(y0f, 0.0f), HM1);
    float y1c = fminf(fmaxf(y1f, 0.0f), HM1);

    float2 m00 = wg(fx00, fy00, x0c, y0c);
    float2 m01 = wg(fx01, fy01, x1c, y0c);
    float2 m10 = wg(fx10, fy10, x0c, y1c);
    float2 m11 = wg(fx11, fy11, x1c, y1c);

    float w00 = axw * ayw, w10 = bxw * ayw, w01 = axw * byw, w11 = bxw * byw;
    float mx = w00 * m00.x + w10 * m01.x + w01 * m10.x + w11 * m11.x;
    float my = w00 * m00.y + w10 * m01.y + w01 * m10.y + w11 * m11.y;
    float keep = (msum >= 0.9999f) ? 1.0f : 0.0f;
    mx *= keep; my *= keep;

    float dx = xf * INV - mx;
    float dy = yf * INV - my;
    return sqrtf(fmaf(dx, dx, fmaf(dy, dy, EPS2)));
}

// Pixel pair (pix, pix+1) from interleaved tile: two adjacent 8B reads at one
// base -> fuses to ds_read2_b64.
__device__ __forceinline__ void ld_quad(const float* t, int pix, v2f& u, v2f& v) {
    u = *(const v2f*)(t + 2 * pix);
    v = *(const v2f*)(t + 2 * pix + 2);
}

__global__ __launch_bounds__(256)
void cycle_loss_kernel(const float* __restrict__ A,   // UV_AtoB
                       const float* __restrict__ B,   // UV_BtoA
                       float* __restrict__ ws,
                       float* __restrict__ out,
                       int use_ws) {
    __shared__ float lds[2 * TILE_FLOATS];   // [0]=A tile, [TILE_FLOATS]=B tile
    __shared__ float wsum[4];

    int tid  = threadIdx.x;
    int lane = tid & 63;
    int wv   = tid >> 6;
    int bx0 = blockIdx.x * 64;
    int by0 = blockIdx.y * OUT_ROWS;
    int b   = blockIdx.z;
    const float* Ab = A + (size_t)b * 2 * HW;
    const float* Bb = B + (size_t)b * 2 * HW;
    int tc0 = bx0 - C_HALO;    // 16B-aligned
    int tr0 = by0 - R_HALO;

    // ---- stage both tensors as interleaved {fx,fy} tiles (round-0) -------
    constexpr int ROW_CHUNKS = TILE_COLS / 4;            // 20
    constexpr int TASKS_PER_T = TILE_ROWS * ROW_CHUNKS;  // 400
    for (int i = tid; i < 2 * TASKS_PER_T; i += 256) {
        int t   = i / TASKS_PER_T;
        int rem = i - t * TASKS_PER_T;
        int lr  = rem / ROW_CHUNKS;
        int lc4 = rem - lr * ROW_CHUNKS;
        int rg = tr0 + lr;
        int cg = tc0 + lc4 * 4;
        if ((unsigned)rg < (unsigned)H && (unsigned)cg < (unsigned)W) {
            const float* src = (t ? Bb : Ab) + rg * W + cg;
            float4 fx = *(const float4*)(src);
            float4 fy = *(const float4*)(src + HW);
            float* dst = &lds[t * TILE_FLOATS + (lr * LSTRIDE + lc4 * 4) * 2];
            *(float4*)(dst)     = make_float4(fx.x, fy.x, fx.y, fy.y);
            *(float4*)(dst + 4) = make_float4(fx.z, fy.z, fx.w, fy.w);
        }
    }
    __syncthreads();

    const float* ldsA = lds;
    const float* ldsB = lds + TILE_FLOATS;
    int x  = bx0 + lane;
    int yb = by0 + wv * 3;        // 3 consecutive rows per thread
    int lxc = lane + C_HALO;
    float xf = (float)x;

    // centers: one ds_read_b64 per tensor per pixel (2-way aliasing = free)
    v2f aC[3], bC[3];
    #pragma unroll
    for (int p = 0; p < 3; ++p) {
        int co = (wv * 3 + p + R_HALO) * LSTRIDE + lxc;
        aC[p] = *(const v2f*)(ldsA + 2 * co);
        bC[p] = *(const v2f*)(ldsB + 2 * co);
    }

    float s = 0.0f;
    #pragma unroll
    for (int p = 0; p < 3; ++p) {
        float yf = (float)(yb + p);
        v2f xy = (v2f){xf, yf};
        DirMeta m1, m2;
        dir_meta(bC[p], xy, m1);   // ABA: outer flow B, gather A
        dir_meta(aC[p], xy, m2);   // BAB: outer flow A, gather B

        // tile-local coords + eligibility (unsigned trick)
        int x1l = m1.xb - tc0, y1l0 = m1.y0 - tr0, y1l1 = m1.y1 - tr0;
        int x2l = m2.xb - tc0, y2l0 = m2.y0 - tr0, y2l1 = m2.y1 - tr0;
        bool e1 = ((unsigned)x1l <= (unsigned)(TILE_COLS - 2))
                & ((unsigned)y1l0 < (unsigned)TILE_ROWS)
                & ((unsigned)y1l1 < (unsigned)TILE_ROWS);
        bool e2 = ((unsigned)x2l <= (unsigned)(TILE_COLS - 2))
                & ((unsigned)y2l0 < (unsigned)TILE_ROWS)
                & ((unsigned)y2l1 < (unsigned)TILE_ROWS);

        v2f u10, v10, u11, v11, u20, v20, u21, v21;
        if (__all(e1 & e2)) {
            ld_quad(ldsA, y1l0 * LSTRIDE + x1l, u10, v10);
            ld_quad(ldsA, y1l1 * LSTRIDE + x1l, u11, v11);
            ld_quad(ldsB, y2l0 * LSTRIDE + x2l, u20, v20);
            ld_quad(ldsB, y2l1 * LSTRIDE + x2l, u21, v21);
        } else {
            // rare: per-lane LDS/global select
            if (e1) {
                ld_quad(ldsA, y1l0 * LSTRIDE + x1l, u10, v10);
                ld_quad(ldsA, y1l1 * LSTRIDE + x1l, u11, v11);
            } else {
                int o0 = m1.y0 * W + m1.xb, o1 = m1.y1 * W + m1.xb;
                float2a rx0 = *(const float2a*)(Ab + o0);
                float2a ry0 = *(const float2a*)(Ab + HW + o0);
                float2a rx1 = *(const float2a*)(Ab + o1);
                float2a ry1 = *(const float2a*)(Ab + HW + o1);
                u10 = (v2f){rx0.x, ry0.x}; v10 = (v2f){rx0.y, ry0.y};
                u11 = (v2f){rx1.x, ry1.x}; v11 = (v2f){rx1.y, ry1.y};
            }
            if (e2) {
                ld_quad(ldsB, y2l0 * LSTRIDE + x2l, u20, v20);
                ld_quad(ldsB, y2l1 * LSTRIDE + x2l, u21, v21);
            } else {
                int o0 = m2.y0 * W + m2.xb, o1 = m2.y1 * W + m2.xb;
                float2a rx0 = *(const float2a*)(Bb + o0);
                float2a ry0 = *(const float2a*)(Bb + HW + o0);
                float2a rx1 = *(const float2a*)(Bb + o1);
                float2a ry1 = *(const float2a*)(Bb + HW + o1);
                u20 = (v2f){rx0.x, ry0.x}; v20 = (v2f){rx0.y, ry0.y};
                u21 = (v2f){rx1.x, ry1.x}; v21 = (v2f){rx1.y, ry1.y};
            }
        }

        bool ok = fast_ok(m1.f0, u10, v10, u11, v11)
                & fast_ok(m2.f0, u20, v20, u21, v21);
        if (__all(ok)) {
            s += fast_eval(m1, u10, v10, u11, v11, bC[p]);
            s += fast_eval(m2, u20, v20, u21, v21, aC[p]);
        } else {
            s += dir_eval(m1, u10, v10, u11, v11, xf, yf);
            s += dir_eval(m2, u20, v20, u21, v21, xf, yf);
        }
    }

    // wave(64) shuffle reduce -> LDS -> one value per block
    #pragma unroll
    for (int o = 32; o > 0; o >>= 1) s += __shfl_down(s, o, 64);
    if (lane == 0) wsum[wv] = s;
    __syncthreads();
    if (tid == 0) {
        float tsum = wsum[0] + wsum[1] + wsum[2] + wsum[3];
        if (use_ws) {
            int bid = (blockIdx.z * gridDim.y + blockIdx.y) * gridDim.x + blockIdx.x;
            ws[bid] = tsum;                      // plain store, no atomics
        } else {
            atomicAdd(out, tsum * (1.0f / ((float)N * (float)H * (float)W)));
        }
    }
}

__global__ __launch_bounds__(256)
void reduce_kernel(const float* __restrict__ ws, float* __restrict__ out) {
    float s = 0.0f;
    for (int i = threadIdx.x; i < NBLOCKS / 4; i += 256) {   // float4: 12 iters
        float4 v = *(const float4*)(ws + 4 * i);
        s += (v.x + v.y) + (v.z + v.w);
    }
    #pragma unroll
    for (int o = 32; o > 0; o >>= 1) s += __shfl_down(s, o, 64);
    __shared__ float wsum[4];
    int lane = threadIdx.x & 63, wv = threadIdx.x >> 6;
    if (lane == 0) wsum[wv] = s;
    __syncthreads();
    if (threadIdx.x == 0) {
        float t = wsum[0] + wsum[1] + wsum[2] + wsum[3];
        out[0] = t * (1.0f / ((float)N * (float)H * (float)W));
    }
}

extern "C" void kernel_launch(void* const* d_in, const int* in_sizes, int n_in,
                              void* d_out, int out_size, void* d_ws, size_t ws_size,
                              hipStream_t stream) {
    const float* A = (const float*)d_in[0];   // UV_AtoB [16,2,768,768]
    const float* B = (const float*)d_in[1];   // UV_BtoA [16,2,768,768]
    float* out = (float*)d_out;               // scalar fp32
    float* ws  = (float*)d_ws;

    int use_ws = (ws_size >= NBLOCKS * sizeof(float)) ? 1 : 0;
    if (!use_ws) hipMemsetAsync(out, 0, sizeof(float), stream);

    dim3 grid(NBLK_X, NBLK_Y, N);             // (12, 64, 16) = 12288 blocks
    cycle_loss_kernel<<<grid, 256, 0, stream>>>(A, B, ws, out, use_ws);
    if (use_ws) reduce_kernel<<<1, 256, 0, stream>>>(ws, out);
}